// Round 5
// baseline (1541.464 us; speedup 1.0000x reference)
//
#include <hip/hip_runtime.h>

#define N_NODES 100000
#define N_EDGES 600000
#define NF 128
#define NG 256
#define GBLK 1563            // ceil(N_NODES/64)
#define NCHUNK 391           // ceil(N_NODES/256)
#define ACHUNK 4
#define HP 132               // padded pool row stride (floats)

typedef _Float16 f16;
typedef f16 half8 __attribute__((ext_vector_type(8)));
typedef f16 half4v __attribute__((ext_vector_type(4)));
typedef float float4v __attribute__((ext_vector_type(4)));

// ---------------- device-scope grid barrier (all blocks co-resident) -------

__device__ __forceinline__ void gsync(int* cnt, int* gen) {
    __syncthreads();
    __threadfence();   // flush this block's writes to device scope
    if (threadIdx.x == 0) {
        int g = __hip_atomic_load(gen, __ATOMIC_RELAXED, __HIP_MEMORY_SCOPE_AGENT);
        int prev = __hip_atomic_fetch_add(cnt, 1, __ATOMIC_ACQ_REL, __HIP_MEMORY_SCOPE_AGENT);
        if (prev == (int)gridDim.x - 1) {
            __hip_atomic_store(cnt, 0, __ATOMIC_RELAXED, __HIP_MEMORY_SCOPE_AGENT);
            __hip_atomic_fetch_add(gen, 1, __ATOMIC_ACQ_REL, __HIP_MEMORY_SCOPE_AGENT);
        } else {
            while (__hip_atomic_load(gen, __ATOMIC_RELAXED, __HIP_MEMORY_SCOPE_AGENT) == g)
                __builtin_amdgcn_s_sleep(16);
        }
    }
    __syncthreads();
    __threadfence();   // acquire: discard stale cached lines
}

// ---------------- agg core: unweighted gather (z pre-scaled by dinv) -------
// FROZEN: at the random-access request-rate ceiling (~43us/pass, R0/R1/R2).

__device__ __forceinline__ void agg_tail(const half8* __restrict__ z8,
                                         const int* __restrict__ col,
                                         int sbase, int fl, int beg, int end,
                                         float acc[8]) {
    for (int c = beg + 16; c < end; c += 16) {
        int ce = c + fl;
        int cv = (ce < end) ? col[ce] : 0;
        int mc = end - c; if (mc > 16) mc = 16;
        for (int j = 0; j < mc; j += 4) {
            int kk = mc - j;
            half8 v0 = {}, v1 = {}, v2 = {}, v3 = {};
            int s0 = __shfl(cv, sbase + j + 0, 64);
            v0 = z8[(size_t)s0 * 16 + fl];
            if (kk > 1) { int s1 = __shfl(cv, sbase + j + 1, 64); v1 = z8[(size_t)s1 * 16 + fl]; }
            if (kk > 2) { int s2 = __shfl(cv, sbase + j + 2, 64); v2 = z8[(size_t)s2 * 16 + fl]; }
            if (kk > 3) { int s3 = __shfl(cv, sbase + j + 3, 64); v3 = z8[(size_t)s3 * 16 + fl]; }
#pragma unroll
            for (int q = 0; q < 8; q++) acc[q] += (float)v0[q];
            if (kk > 1) {
#pragma unroll
                for (int q = 0; q < 8; q++) acc[q] += (float)v1[q];
            }
            if (kk > 2) {
#pragma unroll
                for (int q = 0; q < 8; q++) acc[q] += (float)v2[q];
            }
            if (kk > 3) {
#pragma unroll
                for (int q = 0; q < 8; q++) acc[q] += (float)v3[q];
            }
        }
    }
}

__device__ __forceinline__ void agg_pair(const half8* __restrict__ z8,
                                         const int* __restrict__ col,
                                         int sbase, int fl,
                                         int begA, int endA, int begB, int endB,
                                         int colvA, int colvB,
                                         float accA[8], float accB[8]) {
    int mA = endA - begA; if (mA > 16) mA = 16;
    int mB = endB - begB; if (mB > 16) mB = 16;
    const int mmax = (mA > mB) ? mA : mB;
    for (int j = 0; j < mmax; j += 4) {
        const int kA = mA - j, kB = mB - j;
        half8 vA0 = {}, vA1 = {}, vA2 = {}, vA3 = {};
        half8 vB0 = {}, vB1 = {}, vB2 = {}, vB3 = {};
        if (kA > 0) {
            int s0 = __shfl(colvA, sbase + j + 0, 64);
            vA0 = z8[(size_t)s0 * 16 + fl];
            if (kA > 1) { int s1 = __shfl(colvA, sbase + j + 1, 64); vA1 = z8[(size_t)s1 * 16 + fl]; }
            if (kA > 2) { int s2 = __shfl(colvA, sbase + j + 2, 64); vA2 = z8[(size_t)s2 * 16 + fl]; }
            if (kA > 3) { int s3 = __shfl(colvA, sbase + j + 3, 64); vA3 = z8[(size_t)s3 * 16 + fl]; }
        }
        if (kB > 0) {
            int s0 = __shfl(colvB, sbase + j + 0, 64);
            vB0 = z8[(size_t)s0 * 16 + fl];
            if (kB > 1) { int s1 = __shfl(colvB, sbase + j + 1, 64); vB1 = z8[(size_t)s1 * 16 + fl]; }
            if (kB > 2) { int s2 = __shfl(colvB, sbase + j + 2, 64); vB2 = z8[(size_t)s2 * 16 + fl]; }
            if (kB > 3) { int s3 = __shfl(colvB, sbase + j + 3, 64); vB3 = z8[(size_t)s3 * 16 + fl]; }
        }
        if (kA > 0) {
#pragma unroll
            for (int q = 0; q < 8; q++) accA[q] += (float)vA0[q];
            if (kA > 1) {
#pragma unroll
                for (int q = 0; q < 8; q++) accA[q] += (float)vA1[q];
            }
            if (kA > 2) {
#pragma unroll
                for (int q = 0; q < 8; q++) accA[q] += (float)vA2[q];
            }
            if (kA > 3) {
#pragma unroll
                for (int q = 0; q < 8; q++) accA[q] += (float)vA3[q];
            }
        }
        if (kB > 0) {
#pragma unroll
            for (int q = 0; q < 8; q++) accB[q] += (float)vB0[q];
            if (kB > 1) {
#pragma unroll
                for (int q = 0; q < 8; q++) accB[q] += (float)vB1[q];
            }
            if (kB > 2) {
#pragma unroll
                for (int q = 0; q < 8; q++) accB[q] += (float)vB2[q];
            }
            if (kB > 3) {
#pragma unroll
                for (int q = 0; q < 8; q++) accB[q] += (float)vB3[q];
            }
        }
    }
    if (endA - begA > 16) agg_tail(z8, col, sbase, fl, begA, endA, accA);
    if (endB - begB > 16) agg_tail(z8, col, sbase, fl, begB, endB, accB);
}

// ---------------- per-tile phase bodies (verbatim from R3 kernels) ---------

__device__ void gemm1_tile(int tile, const float* __restrict__ X,
                           const f16* __restrict__ WTH,
                           const float* __restrict__ dinv,
                           f16* __restrict__ Z, char* smem, int t) {
    f16* As = (f16*)smem;                       // 64*136 f16
    float* sdi = (float*)(smem + 64 * 136 * 2);
    const int row0 = tile * 64;
    const int wave = t >> 6;
    const int lane = t & 63;
    const int nl = lane & 15;
    const int quad = lane >> 4;

    auto bofs = [&](int s, int ct) {
        return (size_t)((((wave * 8 + s * 2 + ct) * 64) + lane) << 3);
    };

    half8 cbh[2];
    cbh[0] = *(const half8*)(WTH + bofs(0, 0));
    cbh[1] = *(const half8*)(WTH + bofs(0, 1));

    if (t < 64) sdi[t] = (row0 + t < N_NODES) ? dinv[row0 + t] : 0.f;
#pragma unroll
    for (int q = 0; q < 8; q++) {
        int lin = t + q * 256;
        int r = lin >> 5, c4 = lin & 31;
        float4 v = make_float4(0.f, 0.f, 0.f, 0.f);
        if (row0 + r < N_NODES) v = ((const float4*)(X + (size_t)(row0 + r) * NF))[c4];
        half4v hv = {(f16)v.x, (f16)v.y, (f16)v.z, (f16)v.w};
        *(half4v*)&As[r * 136 + c4 * 4] = hv;
    }
    __syncthreads();

    float4v acc[2][4];
#pragma unroll
    for (int ct = 0; ct < 2; ct++)
#pragma unroll
        for (int rt = 0; rt < 4; rt++) acc[ct][rt] = (float4v)0.f;

#pragma unroll
    for (int s = 0; s < 4; s++) {
        half8 nbh[2];
        if (s < 3) {
            nbh[0] = *(const half8*)(WTH + bofs(s + 1, 0));
            nbh[1] = *(const half8*)(WTH + bofs(s + 1, 1));
        }
        half8 fa[4];
#pragma unroll
        for (int rt = 0; rt < 4; rt++)
            fa[rt] = *(half8*)&As[(rt * 16 + nl) * 136 + s * 32 + quad * 8];
#pragma unroll
        for (int ct = 0; ct < 2; ct++)
#pragma unroll
            for (int rt = 0; rt < 4; rt++)
                acc[ct][rt] = __builtin_amdgcn_mfma_f32_16x16x32_f16(fa[rt], cbh[ct], acc[ct][rt], 0, 0, 0);
        if (s < 3) {
            cbh[0] = nbh[0]; cbh[1] = nbh[1];
        }
    }

    __syncthreads();
#pragma unroll
    for (int ct = 0; ct < 2; ct++)
#pragma unroll
        for (int rt = 0; rt < 4; rt++)
#pragma unroll
            for (int r = 0; r < 4; r++)
                As[(rt * 16 + quad * 4 + r) * 136 + wave * 32 + ct * 16 + nl] =
                    (f16)(acc[ct][rt][r] * sdi[rt * 16 + quad * 4 + r]);
    __syncthreads();
#pragma unroll
    for (int q = 0; q < 4; q++) {
        int lin = t + q * 256;
        int r = lin >> 4, c8 = lin & 15;
        if (row0 + r < N_NODES)
            *(half8*)(Z + (size_t)(row0 + r) * NF + c8 * 8) = *(half8*)&As[r * 136 + c8 * 8];
    }
}

__device__ void agg_gemm_tile(int tile, const f16* __restrict__ z,
                              const float* __restrict__ dinv,
                              const int* __restrict__ row_ptr,
                              const int* __restrict__ col,
                              const float* __restrict__ bias,
                              const f16* __restrict__ WTH,
                              f16* __restrict__ Zout, char* smem, int t) {
    f16* As = (f16*)smem;
    float* sdi = (float*)(smem + 64 * 136 * 2);
    const int slot = t >> 4;
    const int fl = t & 15;
    const int sbase = (t & 48);
    const int n0 = (tile * 16 + slot) * ACHUNK;
    const half8* z8 = (const half8*)z;

    float bb[8];
    {
        float4 b0 = ((const float4*)bias)[fl * 2];
        float4 b1 = ((const float4*)bias)[fl * 2 + 1];
        bb[0] = b0.x; bb[1] = b0.y; bb[2] = b0.z; bb[3] = b0.w;
        bb[4] = b1.x; bb[5] = b1.y; bb[6] = b1.z; bb[7] = b1.w;
    }

    int rp[5];
#pragma unroll
    for (int i = 0; i < 5; i++) {
        int n = n0 + i;
        rp[i] = row_ptr[(n < N_NODES) ? n : N_NODES];
    }
    float dis[4]; half8 selfv[4]; int colv0[4];
#pragma unroll
    for (int i = 0; i < 4; i++) {
        int n = n0 + i;
        bool ok = n < N_NODES;
        half8 zz = {};
        dis[i] = ok ? dinv[n] : 0.f;
        selfv[i] = ok ? z8[(size_t)n * 16 + fl] : zz;
        int ce = rp[i] + fl;
        colv0[i] = (ce < rp[i + 1]) ? col[ce] : 0;
    }
    if (fl == 0) {
#pragma unroll
        for (int i = 0; i < 4; i++) sdi[slot * ACHUNK + i] = dis[i];
    }

#pragma unroll
    for (int p = 0; p < 2; p++) {
        const int iA = 2 * p, iB = 2 * p + 1;
        float accA[8], accB[8];
#pragma unroll
        for (int q = 0; q < 8; q++) {
            accA[q] = (float)selfv[iA][q];
            accB[q] = (float)selfv[iB][q];
        }
        agg_pair(z8, col, sbase, fl, rp[iA], rp[iA + 1], rp[iB], rp[iB + 1],
                 colv0[iA], colv0[iB], accA, accB);
        half8 oA, oB;
#pragma unroll
        for (int q = 0; q < 8; q++) {
            oA[q] = (f16)fmaxf(bb[q] + dis[iA] * accA[q], 0.f);
            oB[q] = (f16)fmaxf(bb[q] + dis[iB] * accB[q], 0.f);
        }
        *(half8*)&As[(slot * ACHUNK + iA) * 136 + fl * 8] = oA;
        *(half8*)&As[(slot * ACHUNK + iB) * 136 + fl * 8] = oB;
    }

    const int wave = t >> 6;
    const int lane = t & 63;
    const int nl = lane & 15;
    const int quad = lane >> 4;
    const int row0 = tile * 64;

    auto bofs = [&](int s, int ct) {
        return (size_t)((((wave * 8 + s * 2 + ct) * 64) + lane) << 3);
    };

    half8 cbh[2];
    cbh[0] = *(const half8*)(WTH + bofs(0, 0));
    cbh[1] = *(const half8*)(WTH + bofs(0, 1));
    __syncthreads();

    float4v acc[2][4];
#pragma unroll
    for (int ct = 0; ct < 2; ct++)
#pragma unroll
        for (int rt = 0; rt < 4; rt++) acc[ct][rt] = (float4v)0.f;

#pragma unroll
    for (int s = 0; s < 4; s++) {
        half8 nbh[2];
        if (s < 3) {
            nbh[0] = *(const half8*)(WTH + bofs(s + 1, 0));
            nbh[1] = *(const half8*)(WTH + bofs(s + 1, 1));
        }
        half8 fa[4];
#pragma unroll
        for (int rt = 0; rt < 4; rt++)
            fa[rt] = *(half8*)&As[(rt * 16 + nl) * 136 + s * 32 + quad * 8];
#pragma unroll
        for (int ct = 0; ct < 2; ct++)
#pragma unroll
            for (int rt = 0; rt < 4; rt++)
                acc[ct][rt] = __builtin_amdgcn_mfma_f32_16x16x32_f16(fa[rt], cbh[ct], acc[ct][rt], 0, 0, 0);
        if (s < 3) {
            cbh[0] = nbh[0]; cbh[1] = nbh[1];
        }
    }

    __syncthreads();
#pragma unroll
    for (int ct = 0; ct < 2; ct++)
#pragma unroll
        for (int rt = 0; rt < 4; rt++)
#pragma unroll
            for (int r = 0; r < 4; r++)
                As[(rt * 16 + quad * 4 + r) * 136 + wave * 32 + ct * 16 + nl] =
                    (f16)(acc[ct][rt][r] * sdi[rt * 16 + quad * 4 + r]);
    __syncthreads();
#pragma unroll
    for (int q = 0; q < 4; q++) {
        int lin = t + q * 256;
        int r = lin >> 4, c8 = lin & 15;
        if (row0 + r < N_NODES)
            *(half8*)(Zout + (size_t)(row0 + r) * NF + c8 * 8) = *(half8*)&As[r * 136 + c8 * 8];
    }
}

__device__ void agg_pool_tile(int tile, const f16* __restrict__ z,
                              const float* __restrict__ dinv,
                              const int* __restrict__ row_ptr,
                              const int* __restrict__ col,
                              const float* __restrict__ bias,
                              const int* __restrict__ batch,
                              float* __restrict__ pooled, char* smem, int t) {
    float* hs = (float*)smem;                   // 64*HP floats
    int* gids = (int*)(smem + 64 * HP * 4);     // 64 ints

    const int slot = t >> 4;
    const int fl = t & 15;
    const int sbase = (t & 48);
    const int n0 = (tile * 16 + slot) * ACHUNK;
    const int base_node = tile * 64;
    const half8* z8 = (const half8*)z;

    float bb[8];
    {
        float4 b0 = ((const float4*)bias)[fl * 2];
        float4 b1 = ((const float4*)bias)[fl * 2 + 1];
        bb[0] = b0.x; bb[1] = b0.y; bb[2] = b0.z; bb[3] = b0.w;
        bb[4] = b1.x; bb[5] = b1.y; bb[6] = b1.z; bb[7] = b1.w;
    }

    if (t < 64) {
        int n = base_node + t;
        gids[t] = (n < N_NODES) ? batch[n] : -1;
    }

    int rp[5];
#pragma unroll
    for (int i = 0; i < 5; i++) {
        int n = n0 + i;
        rp[i] = row_ptr[(n < N_NODES) ? n : N_NODES];
    }
    float dis[4]; half8 selfv[4]; int colv0[4];
#pragma unroll
    for (int i = 0; i < 4; i++) {
        int n = n0 + i;
        bool ok = n < N_NODES;
        half8 zz = {};
        dis[i] = ok ? dinv[n] : 0.f;
        selfv[i] = ok ? z8[(size_t)n * 16 + fl] : zz;
        int ce = rp[i] + fl;
        colv0[i] = (ce < rp[i + 1]) ? col[ce] : 0;
    }

#pragma unroll
    for (int p = 0; p < 2; p++) {
        const int iA = 2 * p, iB = 2 * p + 1;
        float accA[8], accB[8];
#pragma unroll
        for (int q = 0; q < 8; q++) {
            accA[q] = (float)selfv[iA][q];
            accB[q] = (float)selfv[iB][q];
        }
        agg_pair(z8, col, sbase, fl, rp[iA], rp[iA + 1], rp[iB], rp[iB + 1],
                 colv0[iA], colv0[iB], accA, accB);
        float4v a0, a1, b0v, b1v;
#pragma unroll
        for (int q = 0; q < 4; q++) {
            a0[q]  = fmaxf(bb[q]     + dis[iA] * accA[q],     0.f);
            a1[q]  = fmaxf(bb[q + 4] + dis[iA] * accA[q + 4], 0.f);
            b0v[q] = fmaxf(bb[q]     + dis[iB] * accB[q],     0.f);
            b1v[q] = fmaxf(bb[q + 4] + dis[iB] * accB[q + 4], 0.f);
        }
        *(float4v*)&hs[(slot * ACHUNK + iA) * HP + fl * 8]     = a0;
        *(float4v*)&hs[(slot * ACHUNK + iA) * HP + fl * 8 + 4] = a1;
        *(float4v*)&hs[(slot * ACHUNK + iB) * HP + fl * 8]     = b0v;
        *(float4v*)&hs[(slot * ACHUNK + iB) * HP + fl * 8 + 4] = b1v;
    }
    __syncthreads();

    if (t < NF) {
        float acc = 0.f;
        int curg = -1;
        for (int r = 0; r < 64; r++) {
            int g = gids[r];
            if (g < 0) break;
            if (g != curg) {
                if (curg >= 0) atomicAdd(&pooled[curg * NF + t], acc);
                acc = 0.f;
                curg = g;
            }
            acc += hs[r * HP + t];
        }
        if (curg >= 0) atomicAdd(&pooled[curg * NF + t], acc);
    }
}

// ---------------- the mega-kernel: whole forward pass, 1 dispatch ----------

__global__ __launch_bounds__(256, 4) void k_mega(
    const float* __restrict__ x, const int* __restrict__ ei,
    const int* __restrict__ batch,
    const float* __restrict__ W1, const float* __restrict__ b1,
    const float* __restrict__ W2, const float* __restrict__ b2,
    const float* __restrict__ W3, const float* __restrict__ b3,
    const float* __restrict__ W4, const float* __restrict__ b4,
    const float* __restrict__ Ws1, const float* __restrict__ bs1,
    const float* __restrict__ Ws2, const float* __restrict__ bs2,
    f16* __restrict__ bufA, f16* __restrict__ bufB, f16* __restrict__ wtH,
    int* __restrict__ counts, int* __restrict__ row_ptr,
    int* __restrict__ cursor, int* __restrict__ col, int* __restrict__ bsums,
    float* __restrict__ dinv, float* __restrict__ pooled,
    int* ctrl, float* __restrict__ out) {

    __shared__ __align__(16) char smem[64 * HP * 4 + 256];   // 34048 B union
    __shared__ int stile;
    __shared__ int spre;

    const int t = threadIdx.x;
    const int nb = gridDim.x;
    const int gtid = blockIdx.x * 256 + t;
    const int gstride = nb * 256;
    int* cnt = ctrl;
    int* gen = ctrl + 1;
    int* wq  = ctrl + 2;

    // ---- phase Z: zero counts & pooled; wprep (fragment-ordered fp16 W) ---
    for (int i = gtid; i < N_NODES; i += gstride) counts[i] = 0;
    for (int i = gtid; i < NG * NF; i += gstride) pooled[i] = 0.f;
    for (int idx = gtid; idx < 65536; idx += gstride) {
        int layer = idx >> 14;
        int rem = idx & 16383;
        int j = rem & 7;
        int lane = (rem >> 3) & 63;
        int chunk = rem >> 9;
        int wave = chunk >> 3;
        int s = (chunk >> 1) & 3;
        int ct = chunk & 1;
        int n = wave * 32 + ct * 16 + (lane & 15);
        int k = s * 32 + (lane >> 4) * 8 + j;
        const float* W = (layer == 0) ? W1 : (layer == 1) ? W2 : (layer == 2) ? W3 : W4;
        wtH[layer * 16384 + rem] = (f16)W[k * NF + n];
    }
    gsync(cnt, gen);

    // ---- phase 1: degree count -------------------------------------------
    for (int e = gtid; e < N_EDGES; e += gstride)
        atomicAdd(&counts[ei[N_EDGES + e]], 1);
    gsync(cnt, gen);

    // ---- phase 2: scan level 1 (49 groups of 2048) + dinv ----------------
    if (blockIdx.x < 49) {
        int* s = (int*)smem;
        int b = blockIdx.x;
        int base = b * 2048 + t * 8;
        int local[8];
        int sum = 0;
#pragma unroll
        for (int q = 0; q < 8; q++) {
            int idx = base + q;
            int v = (idx < N_NODES) ? counts[idx] : 0;
            if (idx < N_NODES) dinv[idx] = 1.0f / sqrtf((float)(v + 1));
            local[q] = sum;
            sum += v;
        }
        s[t] = sum;
        __syncthreads();
        for (int off = 1; off < 256; off <<= 1) {
            int v = 0;
            if (t >= off) v = s[t - off];
            __syncthreads();
            s[t] += v;
            __syncthreads();
        }
        int excl = s[t] - sum;
#pragma unroll
        for (int q = 0; q < 8; q++) {
            int idx = base + q;
            if (idx < N_NODES) row_ptr[idx] = excl + local[q];
        }
        if (t == 255) bsums[b] = s[255];
    }
    gsync(cnt, gen);

    // ---- phase 3: scan level 2 (fold group prefixes) + layer-1 gemm ------
    for (int c = blockIdx.x; c < NCHUNK; c += nb) {
        if (t == 0) {
            int g = c >> 3;
            int ssum = 0;
            for (int j = 0; j < g; j++) ssum += bsums[j];
            spre = ssum;
        }
        __syncthreads();
        int i = c * 256 + t;
        if (i < N_NODES) {
            int v = row_ptr[i] + spre;
            row_ptr[i] = v;
            cursor[i] = v;
            if (i == 0) row_ptr[N_NODES] = N_EDGES;
        }
        __syncthreads();
    }
    for (;;) {   // Zs0 = (X @ W1) * dinv
        __syncthreads();
        if (t == 0) stile = atomicAdd(&wq[0], 1);
        __syncthreads();
        int tile = stile;
        if (tile >= GBLK) break;
        gemm1_tile(tile, x, wtH, dinv, bufA, smem, t);
    }
    gsync(cnt, gen);

    // ---- phase 4: fill CSR col[] -----------------------------------------
    for (int e = gtid; e < N_EDGES; e += gstride) {
        int d = ei[N_EDGES + e];
        int p = atomicAdd(&cursor[d], 1);
        col[p] = ei[e];
    }
    gsync(cnt, gen);

    // ---- phases 5-7: fused agg(+relu) -> gemm, layers 1-3 ----------------
    for (;;) {
        __syncthreads();
        if (t == 0) stile = atomicAdd(&wq[1], 1);
        __syncthreads();
        int tile = stile;
        if (tile >= GBLK) break;
        agg_gemm_tile(tile, bufA, dinv, row_ptr, col, b1, wtH + 16384, bufB, smem, t);
    }
    gsync(cnt, gen);
    for (;;) {
        __syncthreads();
        if (t == 0) stile = atomicAdd(&wq[2], 1);
        __syncthreads();
        int tile = stile;
        if (tile >= GBLK) break;
        agg_gemm_tile(tile, bufB, dinv, row_ptr, col, b2, wtH + 32768, bufA, smem, t);
    }
    gsync(cnt, gen);
    for (;;) {
        __syncthreads();
        if (t == 0) stile = atomicAdd(&wq[3], 1);
        __syncthreads();
        int tile = stile;
        if (tile >= GBLK) break;
        agg_gemm_tile(tile, bufA, dinv, row_ptr, col, b3, wtH + 49152, bufB, smem, t);
    }
    gsync(cnt, gen);

    // ---- phase 8: final agg + LDS mean-pool partials ---------------------
    for (;;) {
        __syncthreads();
        if (t == 0) stile = atomicAdd(&wq[4], 1);
        __syncthreads();
        int tile = stile;
        if (tile >= GBLK) break;
        agg_pool_tile(tile, bufB, dinv, row_ptr, col, b4, batch, pooled, smem, t);
    }
    gsync(cnt, gen);

    // ---- phase 9: summary MLP --------------------------------------------
    for (int g = blockIdx.x; g < NG; g += nb) {
        float* row = (float*)smem;
        float* red = row + NF;
        int lo = 0, hi = N_NODES;
        while (lo < hi) { int mid = (lo + hi) >> 1; if (batch[mid] < g) lo = mid + 1; else hi = mid; }
        int start = lo;
        hi = N_NODES;
        while (lo < hi) { int mid = (lo + hi) >> 1; if (batch[mid] < g + 1) lo = mid + 1; else hi = mid; }
        float cntg = (float)(lo - start);
        if (t < NF) row[t] = pooled[g * NF + t] / fmaxf(cntg, 1.f);
        __syncthreads();
        if (t < NF) {
            float a = bs1[t];
            for (int k = 0; k < NF; k++) a += row[k] * Ws1[k * NF + t];
            a = fmaxf(a, 0.f);
            red[t] = a * Ws2[t];
        }
        __syncthreads();
        for (int s2 = 64; s2 > 0; s2 >>= 1) {
            if (t < s2) red[t] += red[t + s2];
            __syncthreads();
        }
        if (t == 0) out[g] = red[0] + bs2[0];
        __syncthreads();
    }
}

// ---------------- driver ----------------

extern "C" void kernel_launch(void* const* d_in, const int* in_sizes, int n_in,
                              void* d_out, int out_size, void* d_ws, size_t ws_size,
                              hipStream_t stream) {
    const float* x    = (const float*)d_in[0];
    const int*   ei   = (const int*)d_in[1];
    const int*   batch= (const int*)d_in[2];
    const float* W1 = (const float*)d_in[3];  const float* b1 = (const float*)d_in[4];
    const float* W2 = (const float*)d_in[5];  const float* b2 = (const float*)d_in[6];
    const float* W3 = (const float*)d_in[7];  const float* b3 = (const float*)d_in[8];
    const float* W4 = (const float*)d_in[9];  const float* b4 = (const float*)d_in[10];
    const float* Ws1= (const float*)d_in[11]; const float* bs1= (const float*)d_in[12];
    const float* Ws2= (const float*)d_in[13]; const float* bs2= (const float*)d_in[14];
    float* out = (float*)d_out;

    char* ws = (char*)d_ws;
    size_t off = 0;
    auto alloc = [&](size_t bytes) {
        void* p = ws + off;
        off += (bytes + 255) & ~(size_t)255;
        return p;
    };
    f16*   bufA   = (f16*)alloc((size_t)N_NODES * NF * 2);
    f16*   bufB   = (f16*)alloc((size_t)N_NODES * NF * 2);
    f16*   wtH    = (f16*)alloc((size_t)4 * NF * NF * 2);
    int*   counts = (int*)alloc((size_t)N_NODES * 4);
    int*   row_ptr= (int*)alloc((size_t)(N_NODES + 1) * 4);
    int*   cursor = (int*)alloc((size_t)N_NODES * 4);
    int*   col    = (int*)alloc((size_t)N_EDGES * 4);
    int*   bsums  = (int*)alloc(64 * 4);
    float* dinv   = (float*)alloc((size_t)N_NODES * 4);
    float* pooled = (float*)alloc((size_t)NG * NF * 4);
    int*   ctrl   = (int*)alloc(64);

    // barrier counter + generation + 5 work-queues must start at 0
    hipMemsetAsync(ctrl, 0, 64, stream);

    // grid sized for guaranteed co-residency (barrier counts gridDim.x)
    static int s_grid = 0;
    if (s_grid == 0) {
        int nbk = 0;
        hipError_t err = hipOccupancyMaxActiveBlocksPerMultiprocessor(
            &nbk, reinterpret_cast<const void*>(&k_mega), 256, 0);
        if (err != hipSuccess || nbk < 1) nbk = 1;
        if (nbk > 8) nbk = 8;
        s_grid = nbk * 256;   // 256 CUs on MI355X
    }

    k_mega<<<s_grid, 256, 0, stream>>>(
        x, ei, batch, W1, b1, W2, b2, W3, b3, W4, b4, Ws1, bs1, Ws2, bs2,
        bufA, bufB, wtH, counts, row_ptr, cursor, col, bsums, dinv, pooled,
        ctrl, out);
}

// Round 6
// 1391.279 us; speedup vs baseline: 1.1079x; 1.1079x over previous
//
#include <hip/hip_runtime.h>

#define N_NODES 100000
#define N_EDGES 600000
#define NF 128
#define NG 256
#define GBLK 1563            // ceil(N_NODES/64)
#define EBLK 2344            // ceil(N_EDGES/256)
#define ACHUNK 4
#define HP 132               // padded pool row stride (floats)
#define SFLAG (1 << 30)      // scan publish flag

typedef _Float16 f16;
typedef f16 half8 __attribute__((ext_vector_type(8)));
typedef f16 half4v __attribute__((ext_vector_type(4)));
typedef float float4v __attribute__((ext_vector_type(4)));

// ---------------- agg core: unweighted gather (z pre-scaled by dinv) -------
// FROZEN: at the random-access request-rate ceiling (~43us/pass, R0/R1/R2).

__device__ __forceinline__ void agg_tail(const half8* __restrict__ z8,
                                         const int* __restrict__ col,
                                         int sbase, int fl, int beg, int end,
                                         float acc[8]) {
    for (int c = beg + 16; c < end; c += 16) {
        int ce = c + fl;
        int cv = (ce < end) ? col[ce] : 0;
        int mc = end - c; if (mc > 16) mc = 16;
        for (int j = 0; j < mc; j += 4) {
            int kk = mc - j;
            half8 v0 = {}, v1 = {}, v2 = {}, v3 = {};
            int s0 = __shfl(cv, sbase + j + 0, 64);
            v0 = z8[(size_t)s0 * 16 + fl];
            if (kk > 1) { int s1 = __shfl(cv, sbase + j + 1, 64); v1 = z8[(size_t)s1 * 16 + fl]; }
            if (kk > 2) { int s2 = __shfl(cv, sbase + j + 2, 64); v2 = z8[(size_t)s2 * 16 + fl]; }
            if (kk > 3) { int s3 = __shfl(cv, sbase + j + 3, 64); v3 = z8[(size_t)s3 * 16 + fl]; }
#pragma unroll
            for (int q = 0; q < 8; q++) acc[q] += (float)v0[q];
            if (kk > 1) {
#pragma unroll
                for (int q = 0; q < 8; q++) acc[q] += (float)v1[q];
            }
            if (kk > 2) {
#pragma unroll
                for (int q = 0; q < 8; q++) acc[q] += (float)v2[q];
            }
            if (kk > 3) {
#pragma unroll
                for (int q = 0; q < 8; q++) acc[q] += (float)v3[q];
            }
        }
    }
}

__device__ __forceinline__ void agg_pair(const half8* __restrict__ z8,
                                         const int* __restrict__ col,
                                         int sbase, int fl,
                                         int begA, int endA, int begB, int endB,
                                         int colvA, int colvB,
                                         float accA[8], float accB[8]) {
    int mA = endA - begA; if (mA > 16) mA = 16;
    int mB = endB - begB; if (mB > 16) mB = 16;
    const int mmax = (mA > mB) ? mA : mB;
    for (int j = 0; j < mmax; j += 4) {
        const int kA = mA - j, kB = mB - j;
        half8 vA0 = {}, vA1 = {}, vA2 = {}, vA3 = {};
        half8 vB0 = {}, vB1 = {}, vB2 = {}, vB3 = {};
        if (kA > 0) {
            int s0 = __shfl(colvA, sbase + j + 0, 64);
            vA0 = z8[(size_t)s0 * 16 + fl];
            if (kA > 1) { int s1 = __shfl(colvA, sbase + j + 1, 64); vA1 = z8[(size_t)s1 * 16 + fl]; }
            if (kA > 2) { int s2 = __shfl(colvA, sbase + j + 2, 64); vA2 = z8[(size_t)s2 * 16 + fl]; }
            if (kA > 3) { int s3 = __shfl(colvA, sbase + j + 3, 64); vA3 = z8[(size_t)s3 * 16 + fl]; }
        }
        if (kB > 0) {
            int s0 = __shfl(colvB, sbase + j + 0, 64);
            vB0 = z8[(size_t)s0 * 16 + fl];
            if (kB > 1) { int s1 = __shfl(colvB, sbase + j + 1, 64); vB1 = z8[(size_t)s1 * 16 + fl]; }
            if (kB > 2) { int s2 = __shfl(colvB, sbase + j + 2, 64); vB2 = z8[(size_t)s2 * 16 + fl]; }
            if (kB > 3) { int s3 = __shfl(colvB, sbase + j + 3, 64); vB3 = z8[(size_t)s3 * 16 + fl]; }
        }
        if (kA > 0) {
#pragma unroll
            for (int q = 0; q < 8; q++) accA[q] += (float)vA0[q];
            if (kA > 1) {
#pragma unroll
                for (int q = 0; q < 8; q++) accA[q] += (float)vA1[q];
            }
            if (kA > 2) {
#pragma unroll
                for (int q = 0; q < 8; q++) accA[q] += (float)vA2[q];
            }
            if (kA > 3) {
#pragma unroll
                for (int q = 0; q < 8; q++) accA[q] += (float)vA3[q];
            }
        }
        if (kB > 0) {
#pragma unroll
            for (int q = 0; q < 8; q++) accB[q] += (float)vB0[q];
            if (kB > 1) {
#pragma unroll
                for (int q = 0; q < 8; q++) accB[q] += (float)vB1[q];
            }
            if (kB > 2) {
#pragma unroll
                for (int q = 0; q < 8; q++) accB[q] += (float)vB2[q];
            }
            if (kB > 3) {
#pragma unroll
                for (int q = 0; q < 8; q++) accB[q] += (float)vB3[q];
            }
        }
    }
    if (endA - begA > 16) agg_tail(z8, col, sbase, fl, begA, endA, accA);
    if (endB - begB > 16) agg_tail(z8, col, sbase, fl, begB, endB, accB);
}

// ---------------- D1: init (zero counts/pooled/bsums/ctrl + wprep) ---------

__global__ void k_init(int* __restrict__ counts, float* __restrict__ pooled,
                       int* __restrict__ bsums, int* __restrict__ ctrl,
                       const float* __restrict__ W1, const float* __restrict__ W2,
                       const float* __restrict__ W3, const float* __restrict__ W4,
                       f16* __restrict__ wtH) {
    int gtid = blockIdx.x * 256 + threadIdx.x;
    int gs = gridDim.x * 256;
    for (int i = gtid; i < N_NODES; i += gs) counts[i] = 0;
    for (int i = gtid; i < NG * NF; i += gs) pooled[i] = 0.f;
    if (gtid < 64) bsums[gtid] = 0;
    if (gtid >= 64 && gtid < 80) ctrl[gtid - 64] = 0;
    for (int idx = gtid; idx < 65536; idx += gs) {   // wprep, fragment order
        int layer = idx >> 14;
        int rem = idx & 16383;
        int j = rem & 7;
        int lane = (rem >> 3) & 63;
        int chunk = rem >> 9;
        int wave = chunk >> 3;
        int s = (chunk >> 1) & 3;
        int ct = chunk & 1;
        int n = wave * 32 + ct * 16 + (lane & 15);
        int k = s * 32 + (lane >> 4) * 8 + j;
        const float* W = (layer == 0) ? W1 : (layer == 1) ? W2 : (layer == 2) ? W3 : W4;
        wtH[layer * 16384 + rem] = (f16)W[k * NF + n];
    }
}

// ---------------- D2: degree count ----------------

__global__ void k_count(const int* __restrict__ ei, int* __restrict__ counts) {
    int e = blockIdx.x * 256 + threadIdx.x;
    if (e < N_EDGES) atomicAdd(&counts[ei[N_EDGES + e]], 1);
}

// ---------------- D3: fused scan (decoupled lookback, 49 blocks) -----------
// 49 blocks always co-resident (<< 256 CUs); each publishes its flagged
// block-sum, spin-reads predecessors' (<=48 words), applies prefix locally.

__global__ __launch_bounds__(256) void k_scan(const int* __restrict__ counts,
                                              int* __restrict__ row_ptr,
                                              int* __restrict__ cursor,
                                              int* __restrict__ bsums,
                                              float* __restrict__ dinv) {
    __shared__ int s[256];
    __shared__ int spre;
    int b = blockIdx.x, t = threadIdx.x;
    int base = b * 2048 + t * 8;
    int local[8];
    int sum = 0;
#pragma unroll
    for (int q = 0; q < 8; q++) {
        int idx = base + q;
        int v = (idx < N_NODES) ? counts[idx] : 0;
        if (idx < N_NODES) dinv[idx] = 1.0f / sqrtf((float)(v + 1));
        local[q] = sum;
        sum += v;
    }
    s[t] = sum;
    __syncthreads();
    for (int off = 1; off < 256; off <<= 1) {
        int v = 0;
        if (t >= off) v = s[t - off];
        __syncthreads();
        s[t] += v;
        __syncthreads();
    }
    int excl = s[t] - sum;
    if (t == 255)
        __hip_atomic_store(&bsums[b], s[255] + SFLAG, __ATOMIC_RELEASE,
                           __HIP_MEMORY_SCOPE_AGENT);
    if (t == 0) {
        int pre = 0;
        for (int j = 0; j < b; j++) {
            int v;
            do {
                v = __hip_atomic_load(&bsums[j], __ATOMIC_RELAXED,
                                      __HIP_MEMORY_SCOPE_AGENT);
            } while (v < SFLAG);
            pre += v - SFLAG;
        }
        spre = pre;
    }
    __syncthreads();
#pragma unroll
    for (int q = 0; q < 8; q++) {
        int idx = base + q;
        if (idx < N_NODES) {
            int v = spre + excl + local[q];
            row_ptr[idx] = v;
            cursor[idx] = v;
        }
    }
    if (b == 0 && t == 0) row_ptr[N_NODES] = N_EDGES;
}

// ---------------- D4: role-split fill CSR + layer-1 GEMM -------------------
// blocks [0,GBLK): Zs0 = (X @ W1) * dinv (needs dinv from D3)
// blocks [GBLK,GBLK+EBLK): CSR col fill   (needs cursor from D3)

__global__ __launch_bounds__(256) void k_fill_gemm1(
    const int* __restrict__ ei, int* __restrict__ cursor, int* __restrict__ col,
    const float* __restrict__ X, const f16* __restrict__ WTH,
    const float* __restrict__ dinv, f16* __restrict__ Z) {
    __shared__ __align__(16) f16 As[64 * 136];
    __shared__ float sdi[64];
    const int t = threadIdx.x;

    if (blockIdx.x >= GBLK) {   // fill role
        int e = (blockIdx.x - GBLK) * 256 + t;
        if (e < N_EDGES) {
            int d = ei[N_EDGES + e];
            int p = atomicAdd(&cursor[d], 1);
            col[p] = ei[e];
        }
        return;
    }

    // gemm role (R4 k_gemm1 verbatim)
    const int row0 = blockIdx.x * 64;
    const int wave = t >> 6;
    const int lane = t & 63;
    const int nl = lane & 15;
    const int quad = lane >> 4;

    auto bofs = [&](int s, int ct) {
        return (size_t)((((wave * 8 + s * 2 + ct) * 64) + lane) << 3);
    };

    half8 cbh[2];
    cbh[0] = *(const half8*)(WTH + bofs(0, 0));
    cbh[1] = *(const half8*)(WTH + bofs(0, 1));

    if (t < 64) sdi[t] = (row0 + t < N_NODES) ? dinv[row0 + t] : 0.f;
#pragma unroll
    for (int q = 0; q < 8; q++) {
        int lin = t + q * 256;
        int r = lin >> 5, c4 = lin & 31;
        float4 v = make_float4(0.f, 0.f, 0.f, 0.f);
        if (row0 + r < N_NODES) v = ((const float4*)(X + (size_t)(row0 + r) * NF))[c4];
        half4v hv = {(f16)v.x, (f16)v.y, (f16)v.z, (f16)v.w};
        *(half4v*)&As[r * 136 + c4 * 4] = hv;
    }
    __syncthreads();

    float4v acc[2][4];
#pragma unroll
    for (int ct = 0; ct < 2; ct++)
#pragma unroll
        for (int rt = 0; rt < 4; rt++) acc[ct][rt] = (float4v)0.f;

#pragma unroll
    for (int s = 0; s < 4; s++) {
        half8 nbh[2];
        if (s < 3) {
            nbh[0] = *(const half8*)(WTH + bofs(s + 1, 0));
            nbh[1] = *(const half8*)(WTH + bofs(s + 1, 1));
        }
        half8 fa[4];
#pragma unroll
        for (int rt = 0; rt < 4; rt++)
            fa[rt] = *(half8*)&As[(rt * 16 + nl) * 136 + s * 32 + quad * 8];
#pragma unroll
        for (int ct = 0; ct < 2; ct++)
#pragma unroll
            for (int rt = 0; rt < 4; rt++)
                acc[ct][rt] = __builtin_amdgcn_mfma_f32_16x16x32_f16(fa[rt], cbh[ct], acc[ct][rt], 0, 0, 0);
        if (s < 3) {
            cbh[0] = nbh[0]; cbh[1] = nbh[1];
        }
    }

    __syncthreads();
#pragma unroll
    for (int ct = 0; ct < 2; ct++)
#pragma unroll
        for (int rt = 0; rt < 4; rt++)
#pragma unroll
            for (int r = 0; r < 4; r++)
                As[(rt * 16 + quad * 4 + r) * 136 + wave * 32 + ct * 16 + nl] =
                    (f16)(acc[ct][rt][r] * sdi[rt * 16 + quad * 4 + r]);
    __syncthreads();
#pragma unroll
    for (int q = 0; q < 4; q++) {
        int lin = t + q * 256;
        int r = lin >> 4, c8 = lin & 15;
        if (row0 + r < N_NODES)
            *(half8*)(Z + (size_t)(row0 + r) * NF + c8 * 8) = *(half8*)&As[r * 136 + c8 * 8];
    }
}

// ---------------- D5-7: fused agg(+relu) -> GEMM (R4 verbatim) -------------

__global__ __launch_bounds__(256) void k_agg_gemm(
    const f16* __restrict__ z, const float* __restrict__ dinv,
    const int* __restrict__ row_ptr, const int* __restrict__ col,
    const float* __restrict__ bias, const f16* __restrict__ WTH,
    f16* __restrict__ Zout) {
    __shared__ __align__(16) f16 As[64 * 136];
    __shared__ float sdi[64];

    const int t = threadIdx.x;
    const int slot = t >> 4;
    const int fl = t & 15;
    const int sbase = (t & 48);
    const int n0 = (blockIdx.x * 16 + slot) * ACHUNK;
    const half8* z8 = (const half8*)z;

    float bb[8];
    {
        float4 b0 = ((const float4*)bias)[fl * 2];
        float4 b1 = ((const float4*)bias)[fl * 2 + 1];
        bb[0] = b0.x; bb[1] = b0.y; bb[2] = b0.z; bb[3] = b0.w;
        bb[4] = b1.x; bb[5] = b1.y; bb[6] = b1.z; bb[7] = b1.w;
    }

    int rp[5];
#pragma unroll
    for (int i = 0; i < 5; i++) {
        int n = n0 + i;
        rp[i] = row_ptr[(n < N_NODES) ? n : N_NODES];
    }
    float dis[4]; half8 selfv[4]; int colv0[4];
#pragma unroll
    for (int i = 0; i < 4; i++) {
        int n = n0 + i;
        bool ok = n < N_NODES;
        half8 zz = {};
        dis[i] = ok ? dinv[n] : 0.f;
        selfv[i] = ok ? z8[(size_t)n * 16 + fl] : zz;
        int ce = rp[i] + fl;
        colv0[i] = (ce < rp[i + 1]) ? col[ce] : 0;
    }
    if (fl == 0) {
#pragma unroll
        for (int i = 0; i < 4; i++) sdi[slot * ACHUNK + i] = dis[i];
    }

#pragma unroll
    for (int p = 0; p < 2; p++) {
        const int iA = 2 * p, iB = 2 * p + 1;
        float accA[8], accB[8];
#pragma unroll
        for (int q = 0; q < 8; q++) {
            accA[q] = (float)selfv[iA][q];
            accB[q] = (float)selfv[iB][q];
        }
        agg_pair(z8, col, sbase, fl, rp[iA], rp[iA + 1], rp[iB], rp[iB + 1],
                 colv0[iA], colv0[iB], accA, accB);
        half8 oA, oB;
#pragma unroll
        for (int q = 0; q < 8; q++) {
            oA[q] = (f16)fmaxf(bb[q] + dis[iA] * accA[q], 0.f);
            oB[q] = (f16)fmaxf(bb[q] + dis[iB] * accB[q], 0.f);
        }
        *(half8*)&As[(slot * ACHUNK + iA) * 136 + fl * 8] = oA;
        *(half8*)&As[(slot * ACHUNK + iB) * 136 + fl * 8] = oB;
    }

    const int wave = t >> 6;
    const int lane = t & 63;
    const int nl = lane & 15;
    const int quad = lane >> 4;
    const int row0 = blockIdx.x * 64;

    auto bofs = [&](int s, int ct) {
        return (size_t)((((wave * 8 + s * 2 + ct) * 64) + lane) << 3);
    };

    half8 cbh[2];
    cbh[0] = *(const half8*)(WTH + bofs(0, 0));
    cbh[1] = *(const half8*)(WTH + bofs(0, 1));
    __syncthreads();

    float4v acc[2][4];
#pragma unroll
    for (int ct = 0; ct < 2; ct++)
#pragma unroll
        for (int rt = 0; rt < 4; rt++) acc[ct][rt] = (float4v)0.f;

#pragma unroll
    for (int s = 0; s < 4; s++) {
        half8 nbh[2];
        if (s < 3) {
            nbh[0] = *(const half8*)(WTH + bofs(s + 1, 0));
            nbh[1] = *(const half8*)(WTH + bofs(s + 1, 1));
        }
        half8 fa[4];
#pragma unroll
        for (int rt = 0; rt < 4; rt++)
            fa[rt] = *(half8*)&As[(rt * 16 + nl) * 136 + s * 32 + quad * 8];
#pragma unroll
        for (int ct = 0; ct < 2; ct++)
#pragma unroll
            for (int rt = 0; rt < 4; rt++)
                acc[ct][rt] = __builtin_amdgcn_mfma_f32_16x16x32_f16(fa[rt], cbh[ct], acc[ct][rt], 0, 0, 0);
        if (s < 3) {
            cbh[0] = nbh[0]; cbh[1] = nbh[1];
        }
    }

    __syncthreads();
#pragma unroll
    for (int ct = 0; ct < 2; ct++)
#pragma unroll
        for (int rt = 0; rt < 4; rt++)
#pragma unroll
            for (int r = 0; r < 4; r++)
                As[(rt * 16 + quad * 4 + r) * 136 + wave * 32 + ct * 16 + nl] =
                    (f16)(acc[ct][rt][r] * sdi[rt * 16 + quad * 4 + r]);
    __syncthreads();
#pragma unroll
    for (int q = 0; q < 4; q++) {
        int lin = t + q * 256;
        int r = lin >> 4, c8 = lin & 15;
        if (row0 + r < N_NODES)
            *(half8*)(Zout + (size_t)(row0 + r) * NF + c8 * 8) = *(half8*)&As[r * 136 + c8 * 8];
    }
}

// ---------------- D8: final agg + LDS mean-pool + last-block MLP -----------
// R3's proven agg+pool body (early return replaced by masking so all threads
// reach the tail), then an atomic done-counter; the last block to finish
// runs the 256-graph summary MLP inline (2 graphs at a time, 128 thr each).

__global__ __launch_bounds__(256) void k_agg_pool_mlp(
    const f16* __restrict__ z, const float* __restrict__ dinv,
    const int* __restrict__ row_ptr, const int* __restrict__ col,
    const float* __restrict__ bias, const int* __restrict__ batch,
    float* __restrict__ pooled, int* __restrict__ ctrl,
    const float* __restrict__ Ws1, const float* __restrict__ bs1,
    const float* __restrict__ Ws2, const float* __restrict__ bs2,
    float* __restrict__ out) {
    __shared__ float hs[64 * HP];   // 33792 B; reused by MLP tail
    __shared__ int gids[64];
    __shared__ int slast;

    const int t = threadIdx.x;
    const int slot = t >> 4;
    const int fl = t & 15;
    const int sbase = (t & 48);
    const int n0 = (blockIdx.x * 16 + slot) * ACHUNK;
    const int base_node = blockIdx.x * 64;
    const half8* z8 = (const half8*)z;

    float bb[8];
    {
        float4 b0 = ((const float4*)bias)[fl * 2];
        float4 b1 = ((const float4*)bias)[fl * 2 + 1];
        bb[0] = b0.x; bb[1] = b0.y; bb[2] = b0.z; bb[3] = b0.w;
        bb[4] = b1.x; bb[5] = b1.y; bb[6] = b1.z; bb[7] = b1.w;
    }

    if (t < 64) {
        int n = base_node + t;
        gids[t] = (n < N_NODES) ? batch[n] : -1;
    }

    int rp[5];
#pragma unroll
    for (int i = 0; i < 5; i++) {
        int n = n0 + i;
        rp[i] = row_ptr[(n < N_NODES) ? n : N_NODES];   // OOR -> beg==end
    }
    float dis[4]; half8 selfv[4]; int colv0[4];
#pragma unroll
    for (int i = 0; i < 4; i++) {
        int n = n0 + i;
        bool ok = n < N_NODES;
        half8 zz = {};
        dis[i] = ok ? dinv[n] : 0.f;
        selfv[i] = ok ? z8[(size_t)(ok ? n : 0) * 16 + fl] : zz;
        int ce = rp[i] + fl;
        colv0[i] = (ce < rp[i + 1]) ? col[ce] : 0;
    }

#pragma unroll
    for (int p = 0; p < 2; p++) {
        const int iA = 2 * p, iB = 2 * p + 1;
        float accA[8], accB[8];
#pragma unroll
        for (int q = 0; q < 8; q++) {
            accA[q] = (float)selfv[iA][q];
            accB[q] = (float)selfv[iB][q];
        }
        agg_pair(z8, col, sbase, fl, rp[iA], rp[iA + 1], rp[iB], rp[iB + 1],
                 colv0[iA], colv0[iB], accA, accB);
        float4v a0, a1, b0v, b1v;
#pragma unroll
        for (int q = 0; q < 4; q++) {
            a0[q]  = fmaxf(bb[q]     + dis[iA] * accA[q],     0.f);
            a1[q]  = fmaxf(bb[q + 4] + dis[iA] * accA[q + 4], 0.f);
            b0v[q] = fmaxf(bb[q]     + dis[iB] * accB[q],     0.f);
            b1v[q] = fmaxf(bb[q + 4] + dis[iB] * accB[q + 4], 0.f);
        }
        *(float4v*)&hs[(slot * ACHUNK + iA) * HP + fl * 8]     = a0;
        *(float4v*)&hs[(slot * ACHUNK + iA) * HP + fl * 8 + 4] = a1;
        *(float4v*)&hs[(slot * ACHUNK + iB) * HP + fl * 8]     = b0v;
        *(float4v*)&hs[(slot * ACHUNK + iB) * HP + fl * 8 + 4] = b1v;
    }
    __syncthreads();

    if (t < NF) {
        float acc = 0.f;
        int curg = -1;
        for (int r = 0; r < 64; r++) {
            int g = gids[r];
            if (g < 0) break;
            if (g != curg) {
                if (curg >= 0) atomicAdd(&pooled[curg * NF + t], acc);
                acc = 0.f;
                curg = g;
            }
            acc += hs[r * HP + t];
        }
        if (curg >= 0) atomicAdd(&pooled[curg * NF + t], acc);
    }
    __syncthreads();

    // ---- last-block MLP ----
    if (t == 0) {
        __threadfence();
        int d = __hip_atomic_fetch_add(&ctrl[0], 1, __ATOMIC_ACQ_REL,
                                       __HIP_MEMORY_SCOPE_AGENT);
        slast = (d == (int)gridDim.x - 1) ? 1 : 0;
    }
    __syncthreads();
    if (!slast) return;

    float* row = hs;          // [2][128]
    float* red = hs + 256;    // [2][128]
    const int half = t >> 7;
    const int f = t & 127;
    for (int gp = 0; gp < NG; gp += 2) {
        int g = gp + half;
        int lo = 0, hi = N_NODES;
        while (lo < hi) { int mid = (lo + hi) >> 1; if (batch[mid] < g) lo = mid + 1; else hi = mid; }
        int start = lo;
        hi = N_NODES;
        while (lo < hi) { int mid = (lo + hi) >> 1; if (batch[mid] < g + 1) lo = mid + 1; else hi = mid; }
        float cntg = (float)(lo - start);
        float pv = __hip_atomic_load(&pooled[g * NF + f], __ATOMIC_RELAXED,
                                     __HIP_MEMORY_SCOPE_AGENT);
        row[half * 128 + f] = pv / fmaxf(cntg, 1.f);
        __syncthreads();
        float a = bs1[f];
        for (int k = 0; k < NF; k++) a += row[half * 128 + k] * Ws1[k * NF + f];
        a = fmaxf(a, 0.f);
        red[half * 128 + f] = a * Ws2[f];
        __syncthreads();
        for (int s2 = 64; s2 > 0; s2 >>= 1) {
            if (f < s2) red[half * 128 + f] += red[half * 128 + f + s2];
            __syncthreads();
        }
        if (f == 0) out[g] = red[half * 128] + bs2[0];
        __syncthreads();
    }
}

// ---------------- driver: 7 dispatches ----------------

extern "C" void kernel_launch(void* const* d_in, const int* in_sizes, int n_in,
                              void* d_out, int out_size, void* d_ws, size_t ws_size,
                              hipStream_t stream) {
    const float* x    = (const float*)d_in[0];
    const int*   ei   = (const int*)d_in[1];
    const int*   batch= (const int*)d_in[2];
    const float* W1 = (const float*)d_in[3];  const float* b1 = (const float*)d_in[4];
    const float* W2 = (const float*)d_in[5];  const float* b2 = (const float*)d_in[6];
    const float* W3 = (const float*)d_in[7];  const float* b3 = (const float*)d_in[8];
    const float* W4 = (const float*)d_in[9];  const float* b4 = (const float*)d_in[10];
    const float* Ws1= (const float*)d_in[11]; const float* bs1= (const float*)d_in[12];
    const float* Ws2= (const float*)d_in[13]; const float* bs2= (const float*)d_in[14];
    float* out = (float*)d_out;

    char* ws = (char*)d_ws;
    size_t off = 0;
    auto alloc = [&](size_t bytes) {
        void* p = ws + off;
        off += (bytes + 255) & ~(size_t)255;
        return p;
    };
    f16*   bufA   = (f16*)alloc((size_t)N_NODES * NF * 2);
    f16*   bufB   = (f16*)alloc((size_t)N_NODES * NF * 2);
    f16*   wtH    = (f16*)alloc((size_t)4 * NF * NF * 2);
    int*   counts = (int*)alloc((size_t)N_NODES * 4);
    int*   row_ptr= (int*)alloc((size_t)(N_NODES + 1) * 4);
    int*   cursor = (int*)alloc((size_t)N_NODES * 4);
    int*   col    = (int*)alloc((size_t)N_EDGES * 4);
    int*   bsums  = (int*)alloc(64 * 4);
    float* dinv   = (float*)alloc((size_t)N_NODES * 4);
    float* pooled = (float*)alloc((size_t)NG * NF * 4);
    int*   ctrl   = (int*)alloc(64);

    k_init<<<256, 256, 0, stream>>>(counts, pooled, bsums, ctrl,
                                    W1, W2, W3, W4, wtH);
    k_count<<<EBLK, 256, 0, stream>>>(ei, counts);
    k_scan<<<49, 256, 0, stream>>>(counts, row_ptr, cursor, bsums, dinv);
    k_fill_gemm1<<<GBLK + EBLK, 256, 0, stream>>>(ei, cursor, col,
                                                  x, wtH, dinv, bufA);
    k_agg_gemm<<<GBLK, 256, 0, stream>>>(bufA, dinv, row_ptr, col, b1,
                                         wtH + 16384, bufB);   // Zs1
    k_agg_gemm<<<GBLK, 256, 0, stream>>>(bufB, dinv, row_ptr, col, b2,
                                         wtH + 32768, bufA);   // Zs2
    k_agg_gemm<<<GBLK, 256, 0, stream>>>(bufA, dinv, row_ptr, col, b3,
                                         wtH + 49152, bufB);   // Zs3
    k_agg_pool_mlp<<<GBLK, 256, 0, stream>>>(bufB, dinv, row_ptr, col, b4,
                                             batch, pooled, ctrl,
                                             Ws1, bs1, Ws2, bs2, out);
}

// Round 7
// 367.574 us; speedup vs baseline: 4.1936x; 3.7850x over previous
//
#include <hip/hip_runtime.h>

#define N_NODES 100000
#define N_EDGES 600000
#define NF 128
#define NG 256
#define GBLK 1563            // ceil(N_NODES/64)
#define EBLK 2344            // ceil(N_EDGES/256)
#define ACHUNK 4
#define HP 132               // padded pool row stride (floats)
#define SFLAG (1 << 30)      // scan publish flag

typedef _Float16 f16;
typedef f16 half8 __attribute__((ext_vector_type(8)));
typedef f16 half4v __attribute__((ext_vector_type(4)));
typedef float float4v __attribute__((ext_vector_type(4)));

// ---------------- agg core: unweighted gather (z pre-scaled by dinv) -------
// FROZEN: at the random-access request-rate ceiling (~43us/pass, R0/R1/R2).

__device__ __forceinline__ void agg_tail(const half8* __restrict__ z8,
                                         const int* __restrict__ col,
                                         int sbase, int fl, int beg, int end,
                                         float acc[8]) {
    for (int c = beg + 16; c < end; c += 16) {
        int ce = c + fl;
        int cv = (ce < end) ? col[ce] : 0;
        int mc = end - c; if (mc > 16) mc = 16;
        for (int j = 0; j < mc; j += 4) {
            int kk = mc - j;
            half8 v0 = {}, v1 = {}, v2 = {}, v3 = {};
            int s0 = __shfl(cv, sbase + j + 0, 64);
            v0 = z8[(size_t)s0 * 16 + fl];
            if (kk > 1) { int s1 = __shfl(cv, sbase + j + 1, 64); v1 = z8[(size_t)s1 * 16 + fl]; }
            if (kk > 2) { int s2 = __shfl(cv, sbase + j + 2, 64); v2 = z8[(size_t)s2 * 16 + fl]; }
            if (kk > 3) { int s3 = __shfl(cv, sbase + j + 3, 64); v3 = z8[(size_t)s3 * 16 + fl]; }
#pragma unroll
            for (int q = 0; q < 8; q++) acc[q] += (float)v0[q];
            if (kk > 1) {
#pragma unroll
                for (int q = 0; q < 8; q++) acc[q] += (float)v1[q];
            }
            if (kk > 2) {
#pragma unroll
                for (int q = 0; q < 8; q++) acc[q] += (float)v2[q];
            }
            if (kk > 3) {
#pragma unroll
                for (int q = 0; q < 8; q++) acc[q] += (float)v3[q];
            }
        }
    }
}

__device__ __forceinline__ void agg_pair(const half8* __restrict__ z8,
                                         const int* __restrict__ col,
                                         int sbase, int fl,
                                         int begA, int endA, int begB, int endB,
                                         int colvA, int colvB,
                                         float accA[8], float accB[8]) {
    int mA = endA - begA; if (mA > 16) mA = 16;
    int mB = endB - begB; if (mB > 16) mB = 16;
    const int mmax = (mA > mB) ? mA : mB;
    for (int j = 0; j < mmax; j += 4) {
        const int kA = mA - j, kB = mB - j;
        half8 vA0 = {}, vA1 = {}, vA2 = {}, vA3 = {};
        half8 vB0 = {}, vB1 = {}, vB2 = {}, vB3 = {};
        if (kA > 0) {
            int s0 = __shfl(colvA, sbase + j + 0, 64);
            vA0 = z8[(size_t)s0 * 16 + fl];
            if (kA > 1) { int s1 = __shfl(colvA, sbase + j + 1, 64); vA1 = z8[(size_t)s1 * 16 + fl]; }
            if (kA > 2) { int s2 = __shfl(colvA, sbase + j + 2, 64); vA2 = z8[(size_t)s2 * 16 + fl]; }
            if (kA > 3) { int s3 = __shfl(colvA, sbase + j + 3, 64); vA3 = z8[(size_t)s3 * 16 + fl]; }
        }
        if (kB > 0) {
            int s0 = __shfl(colvB, sbase + j + 0, 64);
            vB0 = z8[(size_t)s0 * 16 + fl];
            if (kB > 1) { int s1 = __shfl(colvB, sbase + j + 1, 64); vB1 = z8[(size_t)s1 * 16 + fl]; }
            if (kB > 2) { int s2 = __shfl(colvB, sbase + j + 2, 64); vB2 = z8[(size_t)s2 * 16 + fl]; }
            if (kB > 3) { int s3 = __shfl(colvB, sbase + j + 3, 64); vB3 = z8[(size_t)s3 * 16 + fl]; }
        }
        if (kA > 0) {
#pragma unroll
            for (int q = 0; q < 8; q++) accA[q] += (float)vA0[q];
            if (kA > 1) {
#pragma unroll
                for (int q = 0; q < 8; q++) accA[q] += (float)vA1[q];
            }
            if (kA > 2) {
#pragma unroll
                for (int q = 0; q < 8; q++) accA[q] += (float)vA2[q];
            }
            if (kA > 3) {
#pragma unroll
                for (int q = 0; q < 8; q++) accA[q] += (float)vA3[q];
            }
        }
        if (kB > 0) {
#pragma unroll
            for (int q = 0; q < 8; q++) accB[q] += (float)vB0[q];
            if (kB > 1) {
#pragma unroll
                for (int q = 0; q < 8; q++) accB[q] += (float)vB1[q];
            }
            if (kB > 2) {
#pragma unroll
                for (int q = 0; q < 8; q++) accB[q] += (float)vB2[q];
            }
            if (kB > 3) {
#pragma unroll
                for (int q = 0; q < 8; q++) accB[q] += (float)vB3[q];
            }
        }
    }
    if (endA - begA > 16) agg_tail(z8, col, sbase, fl, begA, endA, accA);
    if (endB - begB > 16) agg_tail(z8, col, sbase, fl, begB, endB, accB);
}

// ---------------- D1: init (zero counts/pooled/bsums + wprep) --------------

__global__ void k_init(int* __restrict__ counts, float* __restrict__ pooled,
                       int* __restrict__ bsums,
                       const float* __restrict__ W1, const float* __restrict__ W2,
                       const float* __restrict__ W3, const float* __restrict__ W4,
                       f16* __restrict__ wtH) {
    int gtid = blockIdx.x * 256 + threadIdx.x;
    int gs = gridDim.x * 256;
    for (int i = gtid; i < N_NODES; i += gs) counts[i] = 0;
    for (int i = gtid; i < NG * NF; i += gs) pooled[i] = 0.f;
    if (gtid < 64) bsums[gtid] = 0;
    for (int idx = gtid; idx < 65536; idx += gs) {   // wprep, fragment order
        int layer = idx >> 14;
        int rem = idx & 16383;
        int j = rem & 7;
        int lane = (rem >> 3) & 63;
        int chunk = rem >> 9;
        int wave = chunk >> 3;
        int s = (chunk >> 1) & 3;
        int ct = chunk & 1;
        int n = wave * 32 + ct * 16 + (lane & 15);
        int k = s * 32 + (lane >> 4) * 8 + j;
        const float* W = (layer == 0) ? W1 : (layer == 1) ? W2 : (layer == 2) ? W3 : W4;
        wtH[layer * 16384 + rem] = (f16)W[k * NF + n];
    }
}

// ---------------- D2: degree count ----------------

__global__ void k_count(const int* __restrict__ ei, int* __restrict__ counts) {
    int e = blockIdx.x * 256 + threadIdx.x;
    if (e < N_EDGES) atomicAdd(&counts[ei[N_EDGES + e]], 1);
}

// ---------------- D3: fused scan (decoupled lookback, 49 blocks) -----------

__global__ __launch_bounds__(256) void k_scan(const int* __restrict__ counts,
                                              int* __restrict__ row_ptr,
                                              int* __restrict__ cursor,
                                              int* __restrict__ bsums,
                                              float* __restrict__ dinv) {
    __shared__ int s[256];
    __shared__ int spre;
    int b = blockIdx.x, t = threadIdx.x;
    int base = b * 2048 + t * 8;
    int local[8];
    int sum = 0;
#pragma unroll
    for (int q = 0; q < 8; q++) {
        int idx = base + q;
        int v = (idx < N_NODES) ? counts[idx] : 0;
        if (idx < N_NODES) dinv[idx] = 1.0f / sqrtf((float)(v + 1));
        local[q] = sum;
        sum += v;
    }
    s[t] = sum;
    __syncthreads();
    for (int off = 1; off < 256; off <<= 1) {
        int v = 0;
        if (t >= off) v = s[t - off];
        __syncthreads();
        s[t] += v;
        __syncthreads();
    }
    int excl = s[t] - sum;
    if (t == 255)
        __hip_atomic_store(&bsums[b], s[255] + SFLAG, __ATOMIC_RELEASE,
                           __HIP_MEMORY_SCOPE_AGENT);
    if (t == 0) {
        int pre = 0;
        for (int j = 0; j < b; j++) {
            int v;
            do {
                v = __hip_atomic_load(&bsums[j], __ATOMIC_RELAXED,
                                      __HIP_MEMORY_SCOPE_AGENT);
            } while (v < SFLAG);
            pre += v - SFLAG;
        }
        spre = pre;
    }
    __syncthreads();
#pragma unroll
    for (int q = 0; q < 8; q++) {
        int idx = base + q;
        if (idx < N_NODES) {
            int v = spre + excl + local[q];
            row_ptr[idx] = v;
            cursor[idx] = v;
        }
    }
    if (b == 0 && t == 0) row_ptr[N_NODES] = N_EDGES;
}

// ---------------- D4: role-split fill CSR + layer-1 GEMM -------------------

__global__ __launch_bounds__(256) void k_fill_gemm1(
    const int* __restrict__ ei, int* __restrict__ cursor, int* __restrict__ col,
    const float* __restrict__ X, const f16* __restrict__ WTH,
    const float* __restrict__ dinv, f16* __restrict__ Z) {
    __shared__ __align__(16) f16 As[64 * 136];
    __shared__ float sdi[64];
    const int t = threadIdx.x;

    if (blockIdx.x >= GBLK) {   // fill role
        int e = (blockIdx.x - GBLK) * 256 + t;
        if (e < N_EDGES) {
            int d = ei[N_EDGES + e];
            int p = atomicAdd(&cursor[d], 1);
            col[p] = ei[e];
        }
        return;
    }

    // gemm role
    const int row0 = blockIdx.x * 64;
    const int wave = t >> 6;
    const int lane = t & 63;
    const int nl = lane & 15;
    const int quad = lane >> 4;

    auto bofs = [&](int s, int ct) {
        return (size_t)((((wave * 8 + s * 2 + ct) * 64) + lane) << 3);
    };

    half8 cbh[2];
    cbh[0] = *(const half8*)(WTH + bofs(0, 0));
    cbh[1] = *(const half8*)(WTH + bofs(0, 1));

    if (t < 64) sdi[t] = (row0 + t < N_NODES) ? dinv[row0 + t] : 0.f;
#pragma unroll
    for (int q = 0; q < 8; q++) {
        int lin = t + q * 256;
        int r = lin >> 5, c4 = lin & 31;
        float4 v = make_float4(0.f, 0.f, 0.f, 0.f);
        if (row0 + r < N_NODES) v = ((const float4*)(X + (size_t)(row0 + r) * NF))[c4];
        half4v hv = {(f16)v.x, (f16)v.y, (f16)v.z, (f16)v.w};
        *(half4v*)&As[r * 136 + c4 * 4] = hv;
    }
    __syncthreads();

    float4v acc[2][4];
#pragma unroll
    for (int ct = 0; ct < 2; ct++)
#pragma unroll
        for (int rt = 0; rt < 4; rt++) acc[ct][rt] = (float4v)0.f;

#pragma unroll
    for (int s = 0; s < 4; s++) {
        half8 nbh[2];
        if (s < 3) {
            nbh[0] = *(const half8*)(WTH + bofs(s + 1, 0));
            nbh[1] = *(const half8*)(WTH + bofs(s + 1, 1));
        }
        half8 fa[4];
#pragma unroll
        for (int rt = 0; rt < 4; rt++)
            fa[rt] = *(half8*)&As[(rt * 16 + nl) * 136 + s * 32 + quad * 8];
#pragma unroll
        for (int ct = 0; ct < 2; ct++)
#pragma unroll
            for (int rt = 0; rt < 4; rt++)
                acc[ct][rt] = __builtin_amdgcn_mfma_f32_16x16x32_f16(fa[rt], cbh[ct], acc[ct][rt], 0, 0, 0);
        if (s < 3) {
            cbh[0] = nbh[0]; cbh[1] = nbh[1];
        }
    }

    __syncthreads();
#pragma unroll
    for (int ct = 0; ct < 2; ct++)
#pragma unroll
        for (int rt = 0; rt < 4; rt++)
#pragma unroll
            for (int r = 0; r < 4; r++)
                As[(rt * 16 + quad * 4 + r) * 136 + wave * 32 + ct * 16 + nl] =
                    (f16)(acc[ct][rt][r] * sdi[rt * 16 + quad * 4 + r]);
    __syncthreads();
#pragma unroll
    for (int q = 0; q < 4; q++) {
        int lin = t + q * 256;
        int r = lin >> 4, c8 = lin & 15;
        if (row0 + r < N_NODES)
            *(half8*)(Z + (size_t)(row0 + r) * NF + c8 * 8) = *(half8*)&As[r * 136 + c8 * 8];
    }
}

// ---------------- D5-7: fused agg(+relu) -> GEMM ----------------

__global__ __launch_bounds__(256) void k_agg_gemm(
    const f16* __restrict__ z, const float* __restrict__ dinv,
    const int* __restrict__ row_ptr, const int* __restrict__ col,
    const float* __restrict__ bias, const f16* __restrict__ WTH,
    f16* __restrict__ Zout) {
    __shared__ __align__(16) f16 As[64 * 136];
    __shared__ float sdi[64];

    const int t = threadIdx.x;
    const int slot = t >> 4;
    const int fl = t & 15;
    const int sbase = (t & 48);
    const int n0 = (blockIdx.x * 16 + slot) * ACHUNK;
    const half8* z8 = (const half8*)z;

    float bb[8];
    {
        float4 b0 = ((const float4*)bias)[fl * 2];
        float4 b1 = ((const float4*)bias)[fl * 2 + 1];
        bb[0] = b0.x; bb[1] = b0.y; bb[2] = b0.z; bb[3] = b0.w;
        bb[4] = b1.x; bb[5] = b1.y; bb[6] = b1.z; bb[7] = b1.w;
    }

    int rp[5];
#pragma unroll
    for (int i = 0; i < 5; i++) {
        int n = n0 + i;
        rp[i] = row_ptr[(n < N_NODES) ? n : N_NODES];
    }
    float dis[4]; half8 selfv[4]; int colv0[4];
#pragma unroll
    for (int i = 0; i < 4; i++) {
        int n = n0 + i;
        bool ok = n < N_NODES;
        half8 zz = {};
        dis[i] = ok ? dinv[n] : 0.f;
        selfv[i] = ok ? z8[(size_t)n * 16 + fl] : zz;
        int ce = rp[i] + fl;
        colv0[i] = (ce < rp[i + 1]) ? col[ce] : 0;
    }
    if (fl == 0) {
#pragma unroll
        for (int i = 0; i < 4; i++) sdi[slot * ACHUNK + i] = dis[i];
    }

#pragma unroll
    for (int p = 0; p < 2; p++) {
        const int iA = 2 * p, iB = 2 * p + 1;
        float accA[8], accB[8];
#pragma unroll
        for (int q = 0; q < 8; q++) {
            accA[q] = (float)selfv[iA][q];
            accB[q] = (float)selfv[iB][q];
        }
        agg_pair(z8, col, sbase, fl, rp[iA], rp[iA + 1], rp[iB], rp[iB + 1],
                 colv0[iA], colv0[iB], accA, accB);
        half8 oA, oB;
#pragma unroll
        for (int q = 0; q < 8; q++) {
            oA[q] = (f16)fmaxf(bb[q] + dis[iA] * accA[q], 0.f);
            oB[q] = (f16)fmaxf(bb[q] + dis[iB] * accB[q], 0.f);
        }
        *(half8*)&As[(slot * ACHUNK + iA) * 136 + fl * 8] = oA;
        *(half8*)&As[(slot * ACHUNK + iB) * 136 + fl * 8] = oB;
    }

    const int wave = t >> 6;
    const int lane = t & 63;
    const int nl = lane & 15;
    const int quad = lane >> 4;
    const int row0 = blockIdx.x * 64;

    auto bofs = [&](int s, int ct) {
        return (size_t)((((wave * 8 + s * 2 + ct) * 64) + lane) << 3);
    };

    half8 cbh[2];
    cbh[0] = *(const half8*)(WTH + bofs(0, 0));
    cbh[1] = *(const half8*)(WTH + bofs(0, 1));
    __syncthreads();

    float4v acc[2][4];
#pragma unroll
    for (int ct = 0; ct < 2; ct++)
#pragma unroll
        for (int rt = 0; rt < 4; rt++) acc[ct][rt] = (float4v)0.f;

#pragma unroll
    for (int s = 0; s < 4; s++) {
        half8 nbh[2];
        if (s < 3) {
            nbh[0] = *(const half8*)(WTH + bofs(s + 1, 0));
            nbh[1] = *(const half8*)(WTH + bofs(s + 1, 1));
        }
        half8 fa[4];
#pragma unroll
        for (int rt = 0; rt < 4; rt++)
            fa[rt] = *(half8*)&As[(rt * 16 + nl) * 136 + s * 32 + quad * 8];
#pragma unroll
        for (int ct = 0; ct < 2; ct++)
#pragma unroll
            for (int rt = 0; rt < 4; rt++)
                acc[ct][rt] = __builtin_amdgcn_mfma_f32_16x16x32_f16(fa[rt], cbh[ct], acc[ct][rt], 0, 0, 0);
        if (s < 3) {
            cbh[0] = nbh[0]; cbh[1] = nbh[1];
        }
    }

    __syncthreads();
#pragma unroll
    for (int ct = 0; ct < 2; ct++)
#pragma unroll
        for (int rt = 0; rt < 4; rt++)
#pragma unroll
            for (int r = 0; r < 4; r++)
                As[(rt * 16 + quad * 4 + r) * 136 + wave * 32 + ct * 16 + nl] =
                    (f16)(acc[ct][rt][r] * sdi[rt * 16 + quad * 4 + r]);
    __syncthreads();
#pragma unroll
    for (int q = 0; q < 4; q++) {
        int lin = t + q * 256;
        int r = lin >> 4, c8 = lin & 15;
        if (row0 + r < N_NODES)
            *(half8*)(Zout + (size_t)(row0 + r) * NF + c8 * 8) = *(half8*)&As[r * 136 + c8 * 8];
    }
}

// ---------------- D8: final agg + LDS mean-pool (R3-proven) ----------------

__global__ __launch_bounds__(256) void k_agg_pool(
    const f16* __restrict__ z, const float* __restrict__ dinv,
    const int* __restrict__ row_ptr, const int* __restrict__ col,
    const float* __restrict__ bias, const int* __restrict__ batch,
    float* __restrict__ pooled) {
    __shared__ float hs[64 * HP];   // 33792 B
    __shared__ int gids[64];

    const int t = threadIdx.x;
    const int slot = t >> 4;
    const int fl = t & 15;
    const int sbase = (t & 48);
    const int n0 = (blockIdx.x * 16 + slot) * ACHUNK;
    const int base_node = blockIdx.x * 64;
    const half8* z8 = (const half8*)z;

    float bb[8];
    {
        float4 b0 = ((const float4*)bias)[fl * 2];
        float4 b1 = ((const float4*)bias)[fl * 2 + 1];
        bb[0] = b0.x; bb[1] = b0.y; bb[2] = b0.z; bb[3] = b0.w;
        bb[4] = b1.x; bb[5] = b1.y; bb[6] = b1.z; bb[7] = b1.w;
    }

    if (t < 64) {
        int n = base_node + t;
        gids[t] = (n < N_NODES) ? batch[n] : -1;
    }

    int rp[5];
#pragma unroll
    for (int i = 0; i < 5; i++) {
        int n = n0 + i;
        rp[i] = row_ptr[(n < N_NODES) ? n : N_NODES];
    }
    float dis[4]; half8 selfv[4]; int colv0[4];
#pragma unroll
    for (int i = 0; i < 4; i++) {
        int n = n0 + i;
        bool ok = n < N_NODES;
        half8 zz = {};
        dis[i] = ok ? dinv[n] : 0.f;
        selfv[i] = ok ? z8[(size_t)(ok ? n : 0) * 16 + fl] : zz;
        int ce = rp[i] + fl;
        colv0[i] = (ce < rp[i + 1]) ? col[ce] : 0;
    }

#pragma unroll
    for (int p = 0; p < 2; p++) {
        const int iA = 2 * p, iB = 2 * p + 1;
        float accA[8], accB[8];
#pragma unroll
        for (int q = 0; q < 8; q++) {
            accA[q] = (float)selfv[iA][q];
            accB[q] = (float)selfv[iB][q];
        }
        agg_pair(z8, col, sbase, fl, rp[iA], rp[iA + 1], rp[iB], rp[iB + 1],
                 colv0[iA], colv0[iB], accA, accB);
        float4v a0, a1, b0v, b1v;
#pragma unroll
        for (int q = 0; q < 4; q++) {
            a0[q]  = fmaxf(bb[q]     + dis[iA] * accA[q],     0.f);
            a1[q]  = fmaxf(bb[q + 4] + dis[iA] * accA[q + 4], 0.f);
            b0v[q] = fmaxf(bb[q]     + dis[iB] * accB[q],     0.f);
            b1v[q] = fmaxf(bb[q + 4] + dis[iB] * accB[q + 4], 0.f);
        }
        *(float4v*)&hs[(slot * ACHUNK + iA) * HP + fl * 8]     = a0;
        *(float4v*)&hs[(slot * ACHUNK + iA) * HP + fl * 8 + 4] = a1;
        *(float4v*)&hs[(slot * ACHUNK + iB) * HP + fl * 8]     = b0v;
        *(float4v*)&hs[(slot * ACHUNK + iB) * HP + fl * 8 + 4] = b1v;
    }
    __syncthreads();

    if (t < NF) {
        float acc = 0.f;
        int curg = -1;
        for (int r = 0; r < 64; r++) {
            int g = gids[r];
            if (g < 0) break;
            if (g != curg) {
                if (curg >= 0) atomicAdd(&pooled[curg * NF + t], acc);
                acc = 0.f;
                curg = g;
            }
            acc += hs[r * HP + t];
        }
        if (curg >= 0) atomicAdd(&pooled[curg * NF + t], acc);
    }
}

// ---------------- D9: summary MLP (256 parallel blocks) ----------------

__global__ void k_mlp(const float* __restrict__ pooled, const int* __restrict__ batch,
                      const float* __restrict__ Ws1, const float* __restrict__ bs1,
                      const float* __restrict__ Ws2, const float* __restrict__ bs2,
                      float* __restrict__ out) {
    __shared__ float row[NF];
    __shared__ float red[NF];
    int g = blockIdx.x, f = threadIdx.x;
    int lo = 0, hi = N_NODES;
    while (lo < hi) { int mid = (lo + hi) >> 1; if (batch[mid] < g) lo = mid + 1; else hi = mid; }
    int start = lo;
    hi = N_NODES;
    while (lo < hi) { int mid = (lo + hi) >> 1; if (batch[mid] < g + 1) lo = mid + 1; else hi = mid; }
    float cnt = (float)(lo - start);
    row[f] = pooled[g * NF + f] / fmaxf(cnt, 1.f);
    __syncthreads();
    float t = bs1[f];
    for (int k = 0; k < NF; k++) t += row[k] * Ws1[k * NF + f];
    t = fmaxf(t, 0.f);
    red[f] = t * Ws2[f];
    __syncthreads();
    for (int s = 64; s > 0; s >>= 1) {
        if (f < s) red[f] += red[f + s];
        __syncthreads();
    }
    if (f == 0) out[g] = red[0] + bs2[0];
}

// ---------------- driver: 8 dispatches ----------------

extern "C" void kernel_launch(void* const* d_in, const int* in_sizes, int n_in,
                              void* d_out, int out_size, void* d_ws, size_t ws_size,
                              hipStream_t stream) {
    const float* x    = (const float*)d_in[0];
    const int*   ei   = (const int*)d_in[1];
    const int*   batch= (const int*)d_in[2];
    const float* W1 = (const float*)d_in[3];  const float* b1 = (const float*)d_in[4];
    const float* W2 = (const float*)d_in[5];  const float* b2 = (const float*)d_in[6];
    const float* W3 = (const float*)d_in[7];  const float* b3 = (const float*)d_in[8];
    const float* W4 = (const float*)d_in[9];  const float* b4 = (const float*)d_in[10];
    const float* Ws1= (const float*)d_in[11]; const float* bs1= (const float*)d_in[12];
    const float* Ws2= (const float*)d_in[13]; const float* bs2= (const float*)d_in[14];
    float* out = (float*)d_out;

    char* ws = (char*)d_ws;
    size_t off = 0;
    auto alloc = [&](size_t bytes) {
        void* p = ws + off;
        off += (bytes + 255) & ~(size_t)255;
        return p;
    };
    f16*   bufA   = (f16*)alloc((size_t)N_NODES * NF * 2);
    f16*   bufB   = (f16*)alloc((size_t)N_NODES * NF * 2);
    f16*   wtH    = (f16*)alloc((size_t)4 * NF * NF * 2);
    int*   counts = (int*)alloc((size_t)N_NODES * 4);
    int*   row_ptr= (int*)alloc((size_t)(N_NODES + 1) * 4);
    int*   cursor = (int*)alloc((size_t)N_NODES * 4);
    int*   col    = (int*)alloc((size_t)N_EDGES * 4);
    int*   bsums  = (int*)alloc(64 * 4);
    float* dinv   = (float*)alloc((size_t)N_NODES * 4);
    float* pooled = (float*)alloc((size_t)NG * NF * 4);

    k_init<<<256, 256, 0, stream>>>(counts, pooled, bsums,
                                    W1, W2, W3, W4, wtH);
    k_count<<<EBLK, 256, 0, stream>>>(ei, counts);
    k_scan<<<49, 256, 0, stream>>>(counts, row_ptr, cursor, bsums, dinv);
    k_fill_gemm1<<<GBLK + EBLK, 256, 0, stream>>>(ei, cursor, col,
                                                  x, wtH, dinv, bufA);
    k_agg_gemm<<<GBLK, 256, 0, stream>>>(bufA, dinv, row_ptr, col, b1,
                                         wtH + 16384, bufB);   // Zs1
    k_agg_gemm<<<GBLK, 256, 0, stream>>>(bufB, dinv, row_ptr, col, b2,
                                         wtH + 32768, bufA);   // Zs2
    k_agg_gemm<<<GBLK, 256, 0, stream>>>(bufA, dinv, row_ptr, col, b3,
                                         wtH + 49152, bufB);   // Zs3
    k_agg_pool<<<GBLK, 256, 0, stream>>>(bufB, dinv, row_ptr, col, b4,
                                         batch, pooled);
    k_mlp<<<NG, 128, 0, stream>>>(pooled, batch, Ws1, bs1, Ws2, bs2, out);
}